// Round 7
// baseline (203.585 us; speedup 1.0000x reference)
//
#include <hip/hip_runtime.h>
#include <stdint.h>

// ---- AdEx constants ----
#define THRC      (-50.4f)
#define ELC       (-70.6f)
#define V_RESETC  (-70.6f)
#define DT_GL_C   (0.10676156583629893f)   // DT*GL/C
#define DELTATC   (2.0f)
#define DT_C      (0.0035587188612099642f) // DT/C
#define DT_TAUW   (0.006944444444444444f)  // DT/TAUW
#define DTA_TAUW  (0.027777777777777776f)  // DT*A/TAUW
#define BCONST    (0.0805f)
#define EXPCLIP   (281.0f)                 // 30 / DT_GL__C

#define M_TOT 8192
#define UNITS 1024
#define K_TOT 1792   // [Xhi 256 | Xlo 256 | Xhi 256 | Z 1024]
#define CH    (8192*1024)
#define BM 512
#define BN 32
#define SK 256                 // K elems per superstep
#define NSUP (K_TOT / SK)      // 7
#define KSPS (SK / 32)         // 8 K-steps per superstep

typedef __attribute__((ext_vector_type(8))) short s16x8;
typedef __attribute__((ext_vector_type(4))) float f32x4;

__device__ __forceinline__ unsigned short f2bf(float f) {
  union { float f; unsigned int u; } v; v.f = f;
  unsigned int r = v.u + 0x7fffu + ((v.u >> 16) & 1u);  // RNE
  return (unsigned short)(r >> 16);
}
__device__ __forceinline__ float bf2f(unsigned short h) {
  union { unsigned int u; float f; } v; v.u = ((unsigned int)h) << 16; return v.f;
}

__device__ __forceinline__ void gload_lds16(const void* g, void* l) {
  __builtin_amdgcn_global_load_lds(
      (const __attribute__((address_space(1))) void*)g,
      (__attribute__((address_space(3))) void*)l, 16, 0, 0);
}

// ---- build A = [Xhi | Xlo | Xhi | Zbf16], row-major 8192 x 1792 bf16 (LINEAR) ----
__global__ __launch_bounds__(256) void build_a(const float* __restrict__ X,
                                               const float* __restrict__ Z,
                                               unsigned short* __restrict__ A) {
  int o = blockIdx.x * 256 + threadIdx.x;       // octet index, 8192*224 total
  int row = o / 224;
  int c8 = (o - row * 224) * 8;
  const float* src; bool lo = false;
  if (c8 < 256)        { src = X + (size_t)row * 256 + c8; }
  else if (c8 < 512)   { src = X + (size_t)row * 256 + (c8 - 256); lo = true; }
  else if (c8 < 768)   { src = X + (size_t)row * 256 + (c8 - 512); }
  else                 { src = Z + (size_t)row * 1024 + (c8 - 768); }
  float4 f0 = *(const float4*)(src);
  float4 f1 = *(const float4*)(src + 4);
  float fv[8] = {f0.x, f0.y, f0.z, f0.w, f1.x, f1.y, f1.z, f1.w};
  unsigned short h[8];
#pragma unroll
  for (int i = 0; i < 8; ++i) {
    unsigned short hi = f2bf(fv[i]);
    h[i] = lo ? f2bf(fv[i] - bf2f(hi)) : hi;
  }
  uint4 pk;
  pk.x = (unsigned)h[0] | ((unsigned)h[1] << 16);
  pk.y = (unsigned)h[2] | ((unsigned)h[3] << 16);
  pk.z = (unsigned)h[4] | ((unsigned)h[5] << 16);
  pk.w = (unsigned)h[6] | ((unsigned)h[7] << 16);
  *(uint4*)(A + (size_t)row * K_TOT + c8) = pk;
}

// ---- build B^T (N-major 1024 x 1792 bf16): [Wi_hi; Wi_hi; Wi_lo; Wr_nodiag] (LINEAR) ----
__global__ __launch_bounds__(256) void build_b(const float* __restrict__ Wi,
                                               const float* __restrict__ Wr,
                                               unsigned short* __restrict__ BT) {
  __shared__ unsigned short tile[32][33];
  int tx = threadIdx.x & 31, ty = threadIdx.x >> 5;
  int k0 = blockIdx.x * 32, n0 = blockIdx.y * 32;
#pragma unroll
  for (int j = 0; j < 4; ++j) {
    int kk = k0 + ty + j * 8;
    int n  = n0 + tx;
    float f; bool lo = false;
    if (kk < 256)       f = Wi[(size_t)kk * 1024 + n];
    else if (kk < 512)  f = Wi[(size_t)(kk - 256) * 1024 + n];
    else if (kk < 768) { f = Wi[(size_t)(kk - 512) * 1024 + n]; lo = true; }
    else { int kr = kk - 768; f = (kr == n) ? 0.0f : Wr[(size_t)kr * 1024 + n]; }
    unsigned short h = f2bf(f);
    if (lo) h = f2bf(f - bf2f(h));
    tile[ty + j * 8][tx] = h;
  }
  __syncthreads();
#pragma unroll
  for (int j = 0; j < 4; ++j) {
    int n  = n0 + ty + j * 8;
    int kk = k0 + tx;
    BT[(size_t)n * K_TOT + kk] = tile[tx][ty + j * 8];
  }
}

// ---- fused GEMM (i_t) + AdEx epilogue, traffic-minimal ----
// Block = 512 rows x 32 cols, 8 waves; wave w owns rows [64w,64w+64) x all 32 cols
// (acc = 4x2 frags = 32 VGPR). A: global->reg directly (29.4 MB streamed ONCE,
// coalesced, no reuse to capture). B: only re-read operand (M/BM = 16x -> 59 MB);
// staged in LDS as 256-K superchunks [seg][col] (conflict-free quarter-wave-
// contiguous ds_read_b128), double-buffered, ONE __syncthreads per 8 K-steps.
// Low VGPR target => 16 waves/CU; TLP hides latency (m114).
__global__ __launch_bounds__(512, 4) void adex_gemm(
    const unsigned short* __restrict__ A, const unsigned short* __restrict__ BT,
    const float* __restrict__ oV, const int* __restrict__ oR,
    const float* __restrict__ oW, const float* __restrict__ oZ,
    float* __restrict__ out)
{
  __shared__ unsigned short Bs[2][32][32][8];   // [buf][seg][col][8] = 16 KB/buf
  const int tid  = threadIdx.x;
  const int w    = tid >> 6;
  const int lane = tid & 63;
  const int l15  = lane & 15, l4 = lane >> 4;

  // Bijective XCD swizzle (512 % 8 == 0), n-fastest: XCD x gets swz [x*64, x*64+64)
  // = 2 m-strips (2 x 1.84 MB of A) x 32 n-tiles; B window streams through L2.
  const int bid = blockIdx.x;
  const int swz = (bid & 7) * 64 + (bid >> 3);
  const int mt    = swz >> 5;        // 16 m-tiles
  const int ntile = swz & 31;        // 32 n-tiles
  const int rowA0 = mt * BM;
  const int colB0 = ntile * BN;

  // B staging: 1024 16B-units per superchunk; unit u: seg=u>>5, col=u&31.
  // Wave w call0 covers u = w*64+lane, call1 covers u = 512 + w*64+lane
  // (gload_lds dest = uniform base + lane*16).
  const int u0 = tid, u1 = tid + 512;
  const unsigned short* bSrc0 = BT + (size_t)(colB0 + (u0 & 31)) * K_TOT + (u0 >> 5) * 8;
  const unsigned short* bSrc1 = BT + (size_t)(colB0 + (u1 & 31)) * K_TOT + (u1 >> 5) * 8;

#define STAGE_B(buf, k0)                                                      \
  do {                                                                        \
    gload_lds16(bSrc0 + (k0), (unsigned short*)Bs[buf] + w * 512);            \
    gload_lds16(bSrc1 + (k0), (unsigned short*)Bs[buf] + 4096 + w * 512);     \
  } while (0)

  // A fragment pointers (advance by SK per superstep; ks offsets fold into imm)
  const unsigned short* pA0 = A + (size_t)(rowA0 + w * 64 +  0 + l15) * K_TOT + l4 * 8;
  const unsigned short* pA1 = A + (size_t)(rowA0 + w * 64 + 16 + l15) * K_TOT + l4 * 8;
  const unsigned short* pA2 = A + (size_t)(rowA0 + w * 64 + 32 + l15) * K_TOT + l4 * 8;
  const unsigned short* pA3 = A + (size_t)(rowA0 + w * 64 + 48 + l15) * K_TOT + l4 * 8;

  f32x4 acc[4][2];
#pragma unroll
  for (int i = 0; i < 4; ++i)
#pragma unroll
    for (int j = 0; j < 2; ++j) acc[i][j] = (f32x4){0.f, 0.f, 0.f, 0.f};

  STAGE_B(0, 0);
  __syncthreads();                    // superchunk 0 staged

  for (int sup = 0; sup < NSUP; ++sup) {
    const int buf = sup & 1;
    if (sup + 1 < NSUP) STAGE_B(buf ^ 1, (sup + 1) * SK);   // prefetch next chunk
#pragma unroll
    for (int ks = 0; ks < KSPS; ++ks) {
      s16x8 af0 = *(const s16x8*)(pA0 + ks * 32);
      s16x8 af1 = *(const s16x8*)(pA1 + ks * 32);
      s16x8 af2 = *(const s16x8*)(pA2 + ks * 32);
      s16x8 af3 = *(const s16x8*)(pA3 + ks * 32);
      // conflict-free: quarter-wave (16 lanes) reads 256 contiguous bytes
      s16x8 bf0 = *(const s16x8*)(&Bs[buf][ks * 4 + l4][l15][0]);
      s16x8 bf1 = *(const s16x8*)(&Bs[buf][ks * 4 + l4][16 + l15][0]);
      acc[0][0] = __builtin_amdgcn_mfma_f32_16x16x32_bf16(af0, bf0, acc[0][0], 0, 0, 0);
      acc[0][1] = __builtin_amdgcn_mfma_f32_16x16x32_bf16(af0, bf1, acc[0][1], 0, 0, 0);
      acc[1][0] = __builtin_amdgcn_mfma_f32_16x16x32_bf16(af1, bf0, acc[1][0], 0, 0, 0);
      acc[1][1] = __builtin_amdgcn_mfma_f32_16x16x32_bf16(af1, bf1, acc[1][1], 0, 0, 0);
      acc[2][0] = __builtin_amdgcn_mfma_f32_16x16x32_bf16(af2, bf0, acc[2][0], 0, 0, 0);
      acc[2][1] = __builtin_amdgcn_mfma_f32_16x16x32_bf16(af2, bf1, acc[2][1], 0, 0, 0);
      acc[3][0] = __builtin_amdgcn_mfma_f32_16x16x32_bf16(af3, bf0, acc[3][0], 0, 0, 0);
      acc[3][1] = __builtin_amdgcn_mfma_f32_16x16x32_bf16(af3, bf1, acc[3][1], 0, 0, 0);
    }
    pA0 += SK; pA1 += SK; pA2 += SK; pA3 += SK;
    __syncthreads();                  // drains stage loads; next chunk ready
  }
#undef STAGE_B

  // Epilogue: C/D layout col = lane&15, row = (lane>>4)*4 + reg
#pragma unroll
  for (int i = 0; i < 4; ++i) {
    int mBase = rowA0 + w * 64 + i * 16 + l4 * 4;
#pragma unroll
    for (int j = 0; j < 2; ++j) {
      int u = colB0 + j * 16 + l15;
#pragma unroll
      for (int r = 0; r < 4; ++r) {
        int m = mBase + r;
        size_t idx = (size_t)m * UNITS + u;
        float it = acc[i][j][r];
        float ov = oV[idx];
        float ow = oW[idx];
        float oz = oZ[idx];
        int   orr = oR[idx];
        float ex = expf((ov - THRC) * 0.5f);          // /DELTAT
        ex = fminf(ex, EXPCLIP);
        float nv = ov - DT_GL_C * (ov - ELC) + (DT_GL_C * DELTATC) * ex + (it - ow) * DT_C;
        nv = (oz > 0.5f) ? V_RESETC : nv;
        float nw = ow - DT_TAUW * ow + DTA_TAUW * (ov - ELC) + BCONST * oz;
        float nz = (nv > THRC) ? 1.0f : 0.0f;
        if (orr > 0) nz = 0.0f;
        int nr = orr - 1 + (nz > 0.5f ? 5 : 0);
        nr = nr < 0 ? 0 : (nr > 5 ? 5 : nr);
        out[idx]           = nv;
        out[CH + idx]      = nz;
        out[2 * CH + idx]  = (float)nr;
        out[3 * CH + idx]  = nw;
      }
    }
  }
}

extern "C" void kernel_launch(void* const* d_in, const int* in_sizes, int n_in,
                              void* d_out, int out_size, void* d_ws, size_t ws_size,
                              hipStream_t stream) {
  const float* X  = (const float*)d_in[0];
  const float* oV = (const float*)d_in[1];
  const int*   oR = (const int*)d_in[2];
  const float* oW = (const float*)d_in[3];
  const float* oZ = (const float*)d_in[4];
  const float* Wi = (const float*)d_in[5];
  const float* Wr = (const float*)d_in[6];
  unsigned short* Aall = (unsigned short*)d_ws;                       // 29.36 MB
  unsigned short* BT   = Aall + (size_t)M_TOT * K_TOT;                //  3.67 MB
  float* out = (float*)d_out;

  hipLaunchKernelGGL(build_a, dim3((M_TOT * (K_TOT / 8)) / 256), dim3(256), 0, stream, X, oZ, Aall);
  hipLaunchKernelGGL(build_b, dim3(K_TOT / 32, UNITS / 32), dim3(256), 0, stream, Wi, Wr, BT);
  hipLaunchKernelGGL(adex_gemm, dim3((M_TOT / BM) * (UNITS / BN)), dim3(512), 0, stream,
                     Aall, BT, oV, oR, oW, oZ, out);
}

// Round 8
// 133.869 us; speedup vs baseline: 1.5208x; 1.5208x over previous
//
#include <hip/hip_runtime.h>
#include <stdint.h>

// ---- AdEx constants ----
#define THRC      (-50.4f)
#define ELC       (-70.6f)
#define V_RESETC  (-70.6f)
#define DT_GL_C   (0.10676156583629893f)   // DT*GL/C
#define DELTATC   (2.0f)
#define DT_C      (0.0035587188612099642f) // DT/C
#define DT_TAUW   (0.006944444444444444f)  // DT/TAUW
#define DTA_TAUW  (0.027777777777777776f)  // DT*A/TAUW
#define BCONST    (0.0805f)
#define EXPCLIP   (281.0f)                 // 30 / DT_GL__C

#define M_TOT 8192
#define UNITS 1024
#define KX    768                 // [Xhi 256 | Xlo 256 | Xhi 256]
#define KBT   1792                // B rows: [Whi;Whi;Wlo;Wr_nodiag]
#define CH    (8192*1024)
#define BM 256
#define BN 128
#define ZSLAB (M_TOT*16)          // bytes per 128-k bit slab: [8192 rows][16 B]

typedef __attribute__((ext_vector_type(8))) short s16x8;
typedef __attribute__((ext_vector_type(4))) float f32x4;

__device__ __forceinline__ unsigned short f2bf(float f) {
  union { float f; unsigned int u; } v; v.f = f;
  unsigned int r = v.u + 0x7fffu + ((v.u >> 16) & 1u);  // RNE
  return (unsigned short)(r >> 16);
}
__device__ __forceinline__ float bf2f(unsigned short h) {
  union { unsigned int u; float f; } v; v.u = ((unsigned int)h) << 16; return v.f;
}
__device__ __forceinline__ void gload_lds16(const void* g, void* l) {
  __builtin_amdgcn_global_load_lds(
      (const __attribute__((address_space(1))) void*)g,
      (__attribute__((address_space(3))) void*)l, 16, 0, 0);
}
// Swizzle within a 32-elem K-chunk: slot' = slot ^ ((row>>1)&3)  [R2-verified, 0 conflicts]
__device__ __forceinline__ int swz_col(int row, int k) {
  return (k & ~31) | (((((k >> 3) & 3) ^ ((row >> 1) & 3)) << 3)) | (k & 7);
}

// ---- build A_X = [Xhi | Xlo | Xhi], row-major 8192 x 768 bf16, pre-swizzled ----
__global__ __launch_bounds__(256) void build_ax(const float* __restrict__ X,
                                                unsigned short* __restrict__ AX) {
  int o = blockIdx.x * 256 + threadIdx.x;       // octet index, 8192*96 total
  int row = o / 96;
  int c8 = (o - row * 96) * 8;
  const float* src; bool lo = false;
  if (c8 < 256)        { src = X + (size_t)row * 256 + c8; }
  else if (c8 < 512)   { src = X + (size_t)row * 256 + (c8 - 256); lo = true; }
  else                 { src = X + (size_t)row * 256 + (c8 - 512); }
  float4 f0 = *(const float4*)(src);
  float4 f1 = *(const float4*)(src + 4);
  float fv[8] = {f0.x, f0.y, f0.z, f0.w, f1.x, f1.y, f1.z, f1.w};
  unsigned short h[8];
#pragma unroll
  for (int i = 0; i < 8; ++i) {
    unsigned short hi = f2bf(fv[i]);
    h[i] = lo ? f2bf(fv[i] - bf2f(hi)) : hi;
  }
  uint4 pk;
  pk.x = (unsigned)h[0] | ((unsigned)h[1] << 16);
  pk.y = (unsigned)h[2] | ((unsigned)h[3] << 16);
  pk.z = (unsigned)h[4] | ((unsigned)h[5] << 16);
  pk.w = (unsigned)h[6] | ((unsigned)h[7] << 16);
  *(uint4*)(AX + (size_t)row * KX + swz_col(row, c8)) = pk;
}

// ---- build B^T (N-major 1024 x 1792): [Wi_hi; Wi_hi; Wi_lo; Wr_nodiag], pre-swizzled ----
__global__ __launch_bounds__(256) void build_b(const float* __restrict__ Wi,
                                               const float* __restrict__ Wr,
                                               unsigned short* __restrict__ BT) {
  __shared__ unsigned short tile[32][33];
  int tx = threadIdx.x & 31, ty = threadIdx.x >> 5;
  int k0 = blockIdx.x * 32, n0 = blockIdx.y * 32;
#pragma unroll
  for (int j = 0; j < 4; ++j) {
    int kk = k0 + ty + j * 8;
    int n  = n0 + tx;
    float f; bool lo = false;
    if (kk < 256)       f = Wi[(size_t)kk * 1024 + n];
    else if (kk < 512)  f = Wi[(size_t)(kk - 256) * 1024 + n];
    else if (kk < 768) { f = Wi[(size_t)(kk - 512) * 1024 + n]; lo = true; }
    else { int kr = kk - 768; f = (kr == n) ? 0.0f : Wr[(size_t)kr * 1024 + n]; }
    unsigned short h = f2bf(f);
    if (lo) h = f2bf(f - bf2f(h));
    tile[ty + j * 8][tx] = h;
  }
  __syncthreads();
#pragma unroll
  for (int j = 0; j < 4; ++j) {
    int n  = n0 + ty + j * 8;
    int kk = k0 + tx;
    BT[(size_t)n * KBT + swz_col(n, kk)] = tile[tx][ty + j * 8];
  }
}

// ---- build Z bitmap: slabs [g=k/128][row][16 B], bit = old_z > 0.5 ----
__global__ __launch_bounds__(256) void build_zb(const float* __restrict__ Z,
                                                char* __restrict__ Zb) {
  int ge = blockIdx.x * 256 + threadIdx.x;      // element index, 8192*1024 total
  float val = Z[ge];
  unsigned long long mask = __ballot(val > 0.5f);
  if ((threadIdx.x & 63) == 0) {
    int row = ge >> 10;
    int k0  = ge & 1023;                        // multiple of 64
    *(unsigned long long*)(Zb + (size_t)(k0 >> 7) * ZSLAB + row * 16 + ((k0 >> 3) & 15)) = mask;
  }
}

__device__ __forceinline__ s16x8 expand_bits(unsigned zw, int l4) {
  unsigned b = zw >> (l4 * 8);
  s16x8 a;
#pragma unroll
  for (int e = 0; e < 8; ++e)
    a[e] = (short)(((b >> e) & 1u) ? 0x3F80 : 0);   // bf16 1.0 / 0.0
  return a;
}

// ---- fused GEMM (i_t) + AdEx epilogue — VMEM-byte-minimal ----
// 256x128 tile, 256 blocks (1/CU), 8 waves (4m x 2n), wave tile 64x64 (acc 4x4).
// X-part (K=768): bf16 LDS-staged (swizzled). Z-part (K=1024): 1-bit/elem bitmap
// held in registers (uint4/row-chunk), expanded to bf16 {0,1} via VALU — cuts the
// dominant A-operand traffic ~8x. Epilogue reads old_z from the same bitmap.
__global__ __launch_bounds__(512, 2) void adex_gemm(
    const unsigned short* __restrict__ AX, const unsigned short* __restrict__ BT,
    const char* __restrict__ Zb,
    const float* __restrict__ oV, const int* __restrict__ oR,
    const float* __restrict__ oW, float* __restrict__ out)
{
  __shared__ unsigned short S[2][12288];   // [A 256x32 | B 128x32] x2 = 48 KB
  const int tid  = threadIdx.x;
  const int w    = tid >> 6;
  const int lane = tid & 63;
  const int l15  = lane & 15, l4 = lane >> 4;
  const int wm   = w >> 1, wn = w & 1;     // 4m x 2n waves

  const int bid = blockIdx.x;              // nt-inner: same nt -> same XCD -> B L2-shared
  const int mt = bid >> 3, nt = bid & 7;
  const int rowA0 = mt * BM;
  const int colB0 = nt * BN;

  // staging sources (thread t loads 16B unit t; LDS dest linear)
  const int srow = tid >> 2, sslot = tid & 3;
  const unsigned short* aS0 = AX + (size_t)(rowA0 + srow)       * KX  + sslot * 8;
  const unsigned short* aS1 = AX + (size_t)(rowA0 + 128 + srow) * KX  + sslot * 8;
  const unsigned short* bS  = BT + (size_t)(colB0 + srow)       * KBT + sslot * 8;

#define STAGE_A(buf)                                          \
  do { gload_lds16(aS0, &S[buf][0] + tid * 8);                \
       gload_lds16(aS1, &S[buf][0] + 4096 + tid * 8); } while (0)
#define STAGE_B(buf) gload_lds16(bS, &S[buf][0] + 8192 + tid * 8)

  // fragment ds_read offsets (elems), XOR matches pre-swizzled storage
  const int slot = l4 ^ ((l15 >> 1) & 3);
  int offA[4], offB[4];
#pragma unroll
  for (int f = 0; f < 4; ++f) offA[f] = (wm * 64 + f * 16 + l15) * 32 + slot * 8;
#pragma unroll
  for (int f = 0; f < 4; ++f) offB[f] = 8192 + (wn * 64 + f * 16 + l15) * 32 + slot * 8;

  // Z-bitmap register pointers: lane holds rows (wm*64 + i*16 + l15), 16B per g-slab
  const char* zp0 = Zb + (size_t)(rowA0 + wm * 64 +  0 + l15) * 16;
  const char* zp1 = Zb + (size_t)(rowA0 + wm * 64 + 16 + l15) * 16;
  const char* zp2 = Zb + (size_t)(rowA0 + wm * 64 + 32 + l15) * 16;
  const char* zp3 = Zb + (size_t)(rowA0 + wm * 64 + 48 + l15) * 16;

  f32x4 acc[4][4];
#pragma unroll
  for (int i = 0; i < 4; ++i)
#pragma unroll
    for (int j = 0; j < 4; ++j) acc[i][j] = (f32x4){0.f, 0.f, 0.f, 0.f};

  // prologue: stage chunk 0, load Z-slab g=0
  STAGE_A(0); STAGE_B(0);
  uint4 zbE0 = *(const uint4*)zp0, zbE1 = *(const uint4*)zp1;
  uint4 zbE2 = *(const uint4*)zp2, zbE3 = *(const uint4*)zp3;
  asm volatile("s_waitcnt vmcnt(0)" ::: "memory");
  __syncthreads();

  int cur = 0;
  // ---- X phase: 24 K-steps from LDS ----
#pragma unroll 2
  for (int ks = 0; ks < 24; ++ks) {
    if (ks < 23) { aS0 += 32; aS1 += 32; bS += 32; STAGE_A(cur ^ 1); STAGE_B(cur ^ 1); }
    else         { bS += 32; STAGE_B(cur ^ 1); }   // ks=24 (Z phase) needs B only
    const unsigned short* base = &S[cur][0];
    s16x8 af[4], bf[4];
#pragma unroll
    for (int f = 0; f < 4; ++f) af[f] = *(const s16x8*)(base + offA[f]);
#pragma unroll
    for (int f = 0; f < 4; ++f) bf[f] = *(const s16x8*)(base + offB[f]);
#pragma unroll
    for (int i = 0; i < 4; ++i)
#pragma unroll
      for (int j = 0; j < 4; ++j)
        acc[i][j] = __builtin_amdgcn_mfma_f32_16x16x32_bf16(af[i], bf[j], acc[i][j], 0, 0, 0);
    asm volatile("s_waitcnt vmcnt(0)" ::: "memory");
    __syncthreads();
    cur ^= 1;
  }

  // ---- Z phase: 32 K-steps, A from bit-expansion, B from LDS ----
#define ZSTEP(W0, W1, W2, W3, DOSTAGE)                                        \
  do {                                                                        \
    if (DOSTAGE) { bS += 32; STAGE_B(cur ^ 1); }                              \
    const unsigned short* base = &S[cur][0];                                  \
    s16x8 az[4];                                                              \
    az[0] = expand_bits(W0, l4); az[1] = expand_bits(W1, l4);                 \
    az[2] = expand_bits(W2, l4); az[3] = expand_bits(W3, l4);                 \
    s16x8 bf[4];                                                              \
    bf[0] = *(const s16x8*)(base + offB[0]);                                  \
    bf[1] = *(const s16x8*)(base + offB[1]);                                  \
    bf[2] = *(const s16x8*)(base + offB[2]);                                  \
    bf[3] = *(const s16x8*)(base + offB[3]);                                  \
    _Pragma("unroll")                                                         \
    for (int i = 0; i < 4; ++i)                                               \
      _Pragma("unroll")                                                       \
      for (int j = 0; j < 4; ++j)                                             \
        acc[i][j] = __builtin_amdgcn_mfma_f32_16x16x32_bf16(az[i], bf[j], acc[i][j], 0, 0, 0); \
    asm volatile("s_waitcnt vmcnt(0)" ::: "memory");                          \
    __syncthreads();                                                          \
    cur ^= 1;                                                                 \
  } while (0)

  uint4 zbO0, zbO1, zbO2, zbO3;
  for (int gp = 0; gp < 4; ++gp) {
    // g = 2gp (even): prefetch g+1 into O, compute from E
    zp0 += ZSLAB; zp1 += ZSLAB; zp2 += ZSLAB; zp3 += ZSLAB;
    zbO0 = *(const uint4*)zp0; zbO1 = *(const uint4*)zp1;
    zbO2 = *(const uint4*)zp2; zbO3 = *(const uint4*)zp3;
    ZSTEP(zbE0.x, zbE1.x, zbE2.x, zbE3.x, true);
    ZSTEP(zbE0.y, zbE1.y, zbE2.y, zbE3.y, true);
    ZSTEP(zbE0.z, zbE1.z, zbE2.z, zbE3.z, true);
    ZSTEP(zbE0.w, zbE1.w, zbE2.w, zbE3.w, true);
    // g = 2gp+1 (odd): prefetch g+1 into E (if any), compute from O
    if (gp < 3) {
      zp0 += ZSLAB; zp1 += ZSLAB; zp2 += ZSLAB; zp3 += ZSLAB;
      zbE0 = *(const uint4*)zp0; zbE1 = *(const uint4*)zp1;
      zbE2 = *(const uint4*)zp2; zbE3 = *(const uint4*)zp3;
    }
    ZSTEP(zbO0.x, zbO1.x, zbO2.x, zbO3.x, true);
    ZSTEP(zbO0.y, zbO1.y, zbO2.y, zbO3.y, true);
    ZSTEP(zbO0.z, zbO1.z, zbO2.z, zbO3.z, true);
    ZSTEP(zbO0.w, zbO1.w, zbO2.w, zbO3.w, gp < 3);
  }
#undef ZSTEP
#undef STAGE_A
#undef STAGE_B

  // ---- Epilogue: C/D layout col = lane&15, row = (lane>>4)*4 + reg ----
  const char* zslab = Zb + (size_t)nt * ZSLAB;   // block's u-range = one 128-bit slab
#pragma unroll
  for (int i = 0; i < 4; ++i) {
#pragma unroll
    for (int r = 0; r < 4; ++r) {
      int m = rowA0 + wm * 64 + i * 16 + l4 * 4 + r;
      unsigned zwA = *(const unsigned*)(zslab + m * 16 + (wn * 2 + 0) * 4);
      unsigned zwB = *(const unsigned*)(zslab + m * 16 + (wn * 2 + 1) * 4);
#pragma unroll
      for (int j = 0; j < 4; ++j) {
        int u = colB0 + wn * 64 + j * 16 + l15;
        size_t idx = (size_t)m * UNITS + u;
        float it = acc[i][j][r];
        unsigned zw = (j < 2) ? zwA : zwB;
        float oz = ((zw >> ((j & 1) * 16 + l15)) & 1u) ? 1.0f : 0.0f;
        float ov = oV[idx];
        float ow = oW[idx];
        int   orr = oR[idx];
        float ex = expf((ov - THRC) * 0.5f);          // /DELTAT
        ex = fminf(ex, EXPCLIP);
        float nv = ov - DT_GL_C * (ov - ELC) + (DT_GL_C * DELTATC) * ex + (it - ow) * DT_C;
        nv = (oz > 0.5f) ? V_RESETC : nv;
        float nw = ow - DT_TAUW * ow + DTA_TAUW * (ov - ELC) + BCONST * oz;
        float nz = (nv > THRC) ? 1.0f : 0.0f;
        if (orr > 0) nz = 0.0f;
        int nr = orr - 1 + (nz > 0.5f ? 5 : 0);
        nr = nr < 0 ? 0 : (nr > 5 ? 5 : nr);
        out[idx]           = nv;
        out[CH + idx]      = nz;
        out[2 * CH + idx]  = (float)nr;
        out[3 * CH + idx]  = nw;
      }
    }
  }
}

extern "C" void kernel_launch(void* const* d_in, const int* in_sizes, int n_in,
                              void* d_out, int out_size, void* d_ws, size_t ws_size,
                              hipStream_t stream) {
  const float* X  = (const float*)d_in[0];
  const float* oV = (const float*)d_in[1];
  const int*   oR = (const int*)d_in[2];
  const float* oW = (const float*)d_in[3];
  const float* oZ = (const float*)d_in[4];
  const float* Wi = (const float*)d_in[5];
  const float* Wr = (const float*)d_in[6];
  unsigned short* AX = (unsigned short*)d_ws;                   // 8192*768*2  = 12.58 MB
  unsigned short* BT = AX + (size_t)M_TOT * KX;                 // 1024*1792*2 =  3.67 MB
  char*           Zb = (char*)(BT + (size_t)UNITS * KBT);       // 8*8192*16   =  1.00 MB
  float* out = (float*)d_out;

  hipLaunchKernelGGL(build_ax, dim3((M_TOT * (KX / 8)) / 256), dim3(256), 0, stream, X, AX);
  hipLaunchKernelGGL(build_b,  dim3(KBT / 32, UNITS / 32), dim3(256), 0, stream, Wi, Wr, BT);
  hipLaunchKernelGGL(build_zb, dim3((M_TOT * UNITS) / 256), dim3(256), 0, stream, oZ, Zb);
  hipLaunchKernelGGL(adex_gemm, dim3((M_TOT / BM) * (UNITS / BN)), dim3(512), 0, stream,
                     AX, BT, Zb, oV, oR, oW, out);
}

// Round 9
// 132.190 us; speedup vs baseline: 1.5401x; 1.0127x over previous
//
#include <hip/hip_runtime.h>
#include <stdint.h>
#include <type_traits>

// ---- AdEx constants ----
#define THRC      (-50.4f)
#define ELC       (-70.6f)
#define V_RESETC  (-70.6f)
#define DT_GL_C   (0.10676156583629893f)   // DT*GL/C
#define DELTATC   (2.0f)
#define DT_C      (0.0035587188612099642f) // DT/C
#define DT_TAUW   (0.006944444444444444f)  // DT/TAUW
#define DTA_TAUW  (0.027777777777777776f)  // DT*A/TAUW
#define BCONST    (0.0805f)
#define EXPCLIP   (281.0f)                 // 30 / DT_GL__C

#define M_TOT 8192
#define UNITS 1024
#define KX    768                 // [Xhi 256 | Xlo 256 | Xhi 256]
#define CH    (8192*1024)
#define BM 256
#define BN 128
#define ZSLAB (M_TOT*16)          // bytes per 128-k bit slab

typedef __attribute__((ext_vector_type(8))) short s16x8;
typedef __attribute__((ext_vector_type(4))) float f32x4;

__device__ __forceinline__ unsigned short f2bf(float f) {
  union { float f; unsigned int u; } v; v.f = f;
  unsigned int r = v.u + 0x7fffu + ((v.u >> 16) & 1u);  // RNE
  return (unsigned short)(r >> 16);
}
__device__ __forceinline__ float bf2f(unsigned short h) {
  union { unsigned int u; float f; } v; v.u = ((unsigned int)h) << 16; return v.f;
}
__device__ __forceinline__ void gload_lds16(const void* g, void* l) {
  __builtin_amdgcn_global_load_lds(
      (const __attribute__((address_space(1))) void*)g,
      (__attribute__((address_space(3))) void*)l, 16, 0, 0);
}

template <int I, int N, typename F>
__device__ __forceinline__ void unroll_for(F&& f) {
  if constexpr (I < N) { f(std::integral_constant<int, I>{}); unroll_for<I + 1, N>(f); }
}

// ---- build A_X = [Xhi | Xlo | Xhi], row-major 8192 x 768 bf16 (LINEAR) ----
__global__ __launch_bounds__(256) void build_ax(const float* __restrict__ X,
                                                unsigned short* __restrict__ AX) {
  int o = blockIdx.x * 256 + threadIdx.x;       // octet index, 8192*96 total
  int row = o / 96;
  int c8 = (o - row * 96) * 8;
  const float* src; bool lo = false;
  if (c8 < 256)        { src = X + (size_t)row * 256 + c8; }
  else if (c8 < 512)   { src = X + (size_t)row * 256 + (c8 - 256); lo = true; }
  else                 { src = X + (size_t)row * 256 + (c8 - 512); }
  float4 f0 = *(const float4*)(src);
  float4 f1 = *(const float4*)(src + 4);
  float fv[8] = {f0.x, f0.y, f0.z, f0.w, f1.x, f1.y, f1.z, f1.w};
  unsigned short h[8];
#pragma unroll
  for (int i = 0; i < 8; ++i) {
    unsigned short hi = f2bf(fv[i]);
    h[i] = lo ? f2bf(fv[i] - bf2f(hi)) : hi;
  }
  uint4 pk;
  pk.x = (unsigned)h[0] | ((unsigned)h[1] << 16);
  pk.y = (unsigned)h[2] | ((unsigned)h[3] << 16);
  pk.z = (unsigned)h[4] | ((unsigned)h[5] << 16);
  pk.w = (unsigned)h[6] | ((unsigned)h[7] << 16);
  *(uint4*)(AX + (size_t)row * KX + c8) = pk;
}

// ---- build B^T k-chunked: BT2[ksc][kbw][col][8e], k = ksc*128 + kbw*8 + e ----
// rows of B^T: [Wi_hi(256); Wi_hi; Wi_lo; Wr_nodiag(1024)]
__global__ __launch_bounds__(256) void build_b(const float* __restrict__ Wi,
                                               const float* __restrict__ Wr,
                                               unsigned short* __restrict__ BT2) {
  __shared__ unsigned short tile[32][33];
  int tx = threadIdx.x & 31, ty = threadIdx.x >> 5;
  int k0 = blockIdx.x * 32, n0 = blockIdx.y * 32;
#pragma unroll
  for (int j = 0; j < 4; ++j) {
    int kk = k0 + ty + j * 8;
    int n  = n0 + tx;
    float f; bool lo = false;
    if (kk < 256)       f = Wi[(size_t)kk * 1024 + n];
    else if (kk < 512)  f = Wi[(size_t)(kk - 256) * 1024 + n];
    else if (kk < 768) { f = Wi[(size_t)(kk - 512) * 1024 + n]; lo = true; }
    else { int kr = kk - 768; f = (kr == n) ? 0.0f : Wr[(size_t)kr * 1024 + n]; }
    unsigned short h = f2bf(f);
    if (lo) h = f2bf(f - bf2f(h));
    tile[ty + j * 8][tx] = h;
  }
  __syncthreads();
#pragma unroll
  for (int j = 0; j < 4; ++j) {
    int n  = n0 + ty + j * 8;
    int kk = k0 + tx;
    size_t off = (size_t)(kk >> 7) * 131072 + (size_t)((kk >> 3) & 15) * 8192
               + (size_t)n * 8 + (kk & 7);
    BT2[off] = tile[tx][ty + j * 8];
  }
}

// ---- build Z bitmap: slabs [g=k/128][row][16 B], bit = old_z > 0.5 ----
__global__ __launch_bounds__(256) void build_zb(const float* __restrict__ Z,
                                                char* __restrict__ Zb) {
  int ge = blockIdx.x * 256 + threadIdx.x;
  float val = Z[ge];
  unsigned long long mask = __ballot(val > 0.5f);
  if ((threadIdx.x & 63) == 0) {
    int row = ge >> 10;
    int k0  = ge & 1023;
    *(unsigned long long*)(Zb + (size_t)(k0 >> 7) * ZSLAB + row * 16 + ((k0 >> 3) & 15)) = mask;
  }
}

__device__ __forceinline__ s16x8 expand_bits(unsigned zw, int l4) {
  unsigned b = zw >> (l4 * 8);
  s16x8 a;
#pragma unroll
  for (int e = 0; e < 8; ++e)
    a[e] = (short)(((b >> e) & 1u) ? 0x3F80 : 0);   // bf16 1.0 / 0.0
  return a;
}

// ---- fused GEMM (i_t) + AdEx epilogue ----
// 256x128 tile, 256 blocks, 8 waves (4m x 2n), wave 64x64 (acc 4x4).
// ONE barrier per 128-K superstep (14 total), counted vmcnt (never 0 in loop).
// B: LDS [kb][col] chunks (natural conflict-free, no swizzle) via gload_lds from
// k-chunked BT2 (stage source fully coalesced). A: global->reg asm loads, depth-1
// prefetch, all offsets imm. Z-part: 1-bit bitmap expanded in VALU (R8).
__global__ __launch_bounds__(512, 2) void adex_gemm(
    const unsigned short* __restrict__ AX, const unsigned short* __restrict__ BT2,
    const char* __restrict__ Zb,
    const float* __restrict__ oV, const int* __restrict__ oR,
    const float* __restrict__ oW, float* __restrict__ out)
{
  __shared__ unsigned short Bs[2][16][128][8];   // 64 KB: [buf][kb][col][8]
  const int tid  = threadIdx.x;
  const int w    = tid >> 6;
  const int lane = tid & 63;
  const int l15  = lane & 15, l4 = lane >> 4;
  const int wm   = w >> 1, wn = w & 1;

  const int bid = blockIdx.x;
  const int nt = bid & 7, mt = bid >> 3;     // nt = XCD id -> B panel L2-resident
  const int rowA0 = mt * BM, colB0 = nt * BN;

  // B staging: thread t stages unit u = i*512+t -> kb = i*4+(t>>7), col = t&127
  const unsigned short* bSrc = BT2 + (size_t)(tid >> 7) * 8192
                             + ((size_t)colB0 + (tid & 127)) * 8;
  char* bDst = (char*)&Bs[0][0][0][0] + tid * 16;

#define STAGE_B(buf, ss)                                                     \
  do {                                                                       \
    const unsigned short* s_ = bSrc + (size_t)(ss) * 131072;                 \
    char* d_ = bDst + (buf) * 32768;                                         \
    gload_lds16(s_,         d_);                                             \
    gload_lds16(s_ + 32768, d_ + 8192);                                      \
    gload_lds16(s_ + 65536, d_ + 16384);                                     \
    gload_lds16(s_ + 98304, d_ + 24576);                                     \
  } while (0)

  // A fragment pointers (row-major AX); per-kstep offset = g*64 B (imm <= 1472)
  const unsigned short* pA0 = AX + (size_t)(rowA0 + wm * 64 +  0 + l15) * KX + l4 * 8;
  const unsigned short* pA1 = AX + (size_t)(rowA0 + wm * 64 + 16 + l15) * KX + l4 * 8;
  const unsigned short* pA2 = AX + (size_t)(rowA0 + wm * 64 + 32 + l15) * KX + l4 * 8;
  const unsigned short* pA3 = AX + (size_t)(rowA0 + wm * 64 + 48 + l15) * KX + l4 * 8;

#define LD(dst, ptr, off)                                        \
  asm volatile("global_load_dwordx4 %0, %1, off offset:%2"       \
               : "=v"(dst) : "v"(ptr), "n"(off) : "memory")
#define LDZ(dst, ptr)                                            \
  asm volatile("global_load_dwordx4 %0, %1, off"                 \
               : "=v"(dst) : "v"(ptr) : "memory")

  // Z bitmap pointers (invariant: point at next slab to load)
  const char* zp0 = Zb + (size_t)(rowA0 + wm * 64 +  0 + l15) * 16;
  const char* zp1 = Zb + (size_t)(rowA0 + wm * 64 + 16 + l15) * 16;
  const char* zp2 = Zb + (size_t)(rowA0 + wm * 64 + 32 + l15) * 16;
  const char* zp3 = Zb + (size_t)(rowA0 + wm * 64 + 48 + l15) * 16;
  uint4 zr0, zr1, zr2, zr3;

  f32x4 acc[4][4];
#pragma unroll
  for (int i = 0; i < 4; ++i)
#pragma unroll
    for (int j = 0; j < 4; ++j) acc[i][j] = (f32x4){0.f, 0.f, 0.f, 0.f};

#define MFMA16(a0,a1,a2,a3, b0,b1,b2,b3)                                        \
  do {                                                                          \
    acc[0][0]=__builtin_amdgcn_mfma_f32_16x16x32_bf16(a0,b0,acc[0][0],0,0,0);   \
    acc[0][1]=__builtin_amdgcn_mfma_f32_16x16x32_bf16(a0,b1,acc[0][1],0,0,0);   \
    acc[0][2]=__builtin_amdgcn_mfma_f32_16x16x32_bf16(a0,b2,acc[0][2],0,0,0);   \
    acc[0][3]=__builtin_amdgcn_mfma_f32_16x16x32_bf16(a0,b3,acc[0][3],0,0,0);   \
    acc[1][0]=__builtin_amdgcn_mfma_f32_16x16x32_bf16(a1,b0,acc[1][0],0,0,0);   \
    acc[1][1]=__builtin_amdgcn_mfma_f32_16x16x32_bf16(a1,b1,acc[1][1],0,0,0);   \
    acc[1][2]=__builtin_amdgcn_mfma_f32_16x16x32_bf16(a1,b2,acc[1][2],0,0,0);   \
    acc[1][3]=__builtin_amdgcn_mfma_f32_16x16x32_bf16(a1,b3,acc[1][3],0,0,0);   \
    acc[2][0]=__builtin_amdgcn_mfma_f32_16x16x32_bf16(a2,b0,acc[2][0],0,0,0);   \
    acc[2][1]=__builtin_amdgcn_mfma_f32_16x16x32_bf16(a2,b1,acc[2][1],0,0,0);   \
    acc[2][2]=__builtin_amdgcn_mfma_f32_16x16x32_bf16(a2,b2,acc[2][2],0,0,0);   \
    acc[2][3]=__builtin_amdgcn_mfma_f32_16x16x32_bf16(a2,b3,acc[2][3],0,0,0);   \
    acc[3][0]=__builtin_amdgcn_mfma_f32_16x16x32_bf16(a3,b0,acc[3][0],0,0,0);   \
    acc[3][1]=__builtin_amdgcn_mfma_f32_16x16x32_bf16(a3,b1,acc[3][1],0,0,0);   \
    acc[3][2]=__builtin_amdgcn_mfma_f32_16x16x32_bf16(a3,b2,acc[3][2],0,0,0);   \
    acc[3][3]=__builtin_amdgcn_mfma_f32_16x16x32_bf16(a3,b3,acc[3][3],0,0,0);   \
  } while (0)

#define BREAD(bf, buf, ksc)                                                     \
  do {                                                                          \
    const unsigned short* bb_ = &Bs[buf][0][0][0] + ((ksc) * 4 + l4) * 1024     \
                              + (wn * 64 + l15) * 8;                            \
    bf[0] = *(const s16x8*)(bb_);                                               \
    bf[1] = *(const s16x8*)(bb_ + 128);                                         \
    bf[2] = *(const s16x8*)(bb_ + 256);                                         \
    bf[3] = *(const s16x8*)(bb_ + 384);                                         \
  } while (0)

  s16x8 fa[2][4];

  // ---- prologue: stage B(ss0) into buf0, issue A(g=0) ----
  STAGE_B(0, 0);
  LD(fa[0][0], pA0, 0); LD(fa[0][1], pA1, 0);
  LD(fa[0][2], pA2, 0); LD(fa[0][3], pA3, 0);
  asm volatile("s_waitcnt vmcnt(4)" ::: "memory");     // B done; A(0) in flight
  __builtin_amdgcn_sched_barrier(0);
  __builtin_amdgcn_s_barrier();

  // ---- X phase: 24 ksteps (6 supersteps x 4) ----
  unroll_for<0, 24>([&](auto G) {
    constexpr int g = decltype(G)::value;
    constexpr int ks = g & 3, ss = g >> 2, buf = ss & 1, cur = g & 1;
    if constexpr (g + 1 < 24) {
      constexpr int imm = (g + 1) * 64;
      LD(fa[cur ^ 1][0], pA0, imm); LD(fa[cur ^ 1][1], pA1, imm);
      LD(fa[cur ^ 1][2], pA2, imm); LD(fa[cur ^ 1][3], pA3, imm);
    } else {
      LDZ(zr0, zp0); LDZ(zr1, zp1); LDZ(zr2, zp2); LDZ(zr3, zp3);
      zp0 += ZSLAB; zp1 += ZSLAB; zp2 += ZSLAB; zp3 += ZSLAB;
    }
    if constexpr (ks == 1) STAGE_B(buf ^ 1, ss + 1);
    asm volatile("s_waitcnt vmcnt(%0)" :: "n"((ks == 0 || ks == 3) ? 4 : 8) : "memory");
    __builtin_amdgcn_sched_barrier(0);
    s16x8 bf[4];
    BREAD(bf, buf, ks);
    MFMA16(fa[cur][0], fa[cur][1], fa[cur][2], fa[cur][3], bf[0], bf[1], bf[2], bf[3]);
    if constexpr (ks == 3) __builtin_amdgcn_s_barrier();
  });

  // ---- Z phase: 8 supersteps (bitmap A, LDS B) ----
  unroll_for<0, 8>([&](auto ZG) {
    constexpr int zg = decltype(ZG)::value;
    constexpr int ss = 6 + zg, buf = ss & 1;
    if constexpr (zg < 7) STAGE_B(buf ^ 1, ss + 1);
    asm volatile("s_waitcnt vmcnt(%0)" :: "n"(zg < 7 ? 4 : 0) : "memory");
    __builtin_amdgcn_sched_barrier(0);
    {
      s16x8 az0, az1, az2, az3, bf[4];
      az0 = expand_bits(zr0.x, l4); az1 = expand_bits(zr1.x, l4);
      az2 = expand_bits(zr2.x, l4); az3 = expand_bits(zr3.x, l4);
      BREAD(bf, buf, 0); MFMA16(az0, az1, az2, az3, bf[0], bf[1], bf[2], bf[3]);
      az0 = expand_bits(zr0.y, l4); az1 = expand_bits(zr1.y, l4);
      az2 = expand_bits(zr2.y, l4); az3 = expand_bits(zr3.y, l4);
      BREAD(bf, buf, 1); MFMA16(az0, az1, az2, az3, bf[0], bf[1], bf[2], bf[3]);
      az0 = expand_bits(zr0.z, l4); az1 = expand_bits(zr1.z, l4);
      az2 = expand_bits(zr2.z, l4); az3 = expand_bits(zr3.z, l4);
      BREAD(bf, buf, 2); MFMA16(az0, az1, az2, az3, bf[0], bf[1], bf[2], bf[3]);
      az0 = expand_bits(zr0.w, l4); az1 = expand_bits(zr1.w, l4);
      az2 = expand_bits(zr2.w, l4); az3 = expand_bits(zr3.w, l4);
      BREAD(bf, buf, 3); MFMA16(az0, az1, az2, az3, bf[0], bf[1], bf[2], bf[3]);
    }
    if constexpr (zg < 7) {
      LDZ(zr0, zp0); LDZ(zr1, zp1); LDZ(zr2, zp2); LDZ(zr3, zp3);
      zp0 += ZSLAB; zp1 += ZSLAB; zp2 += ZSLAB; zp3 += ZSLAB;
      asm volatile("s_waitcnt vmcnt(4)" ::: "memory");   // B staged; Znext in flight
      __builtin_amdgcn_sched_barrier(0);
      __builtin_amdgcn_s_barrier();
    }
  });
#undef STAGE_B
#undef LD
#undef LDZ
#undef MFMA16
#undef BREAD

  // ---- Epilogue: C/D layout col = lane&15, row = (lane>>4)*4 + reg ----
  const char* zslab = Zb + (size_t)nt * ZSLAB;
#pragma unroll
  for (int i = 0; i < 4; ++i) {
#pragma unroll
    for (int r = 0; r < 4; ++r) {
      int m = rowA0 + wm * 64 + i * 16 + l4 * 4 + r;
      unsigned zwA = *(const unsigned*)(zslab + m * 16 + (wn * 2 + 0) * 4);
      unsigned zwB = *(const unsigned*)(zslab + m * 16 + (wn * 2 + 1) * 4);
#pragma unroll
      for (int j = 0; j < 4; ++j) {
        int u = colB0 + wn * 64 + j * 16 + l15;
        size_t idx = (size_t)m * UNITS + u;
        float it = acc[i][j][r];
        unsigned zw = (j < 2) ? zwA : zwB;
        float oz = ((zw >> ((j & 1) * 16 + l15)) & 1u) ? 1.0f : 0.0f;
        float ov = oV[idx];
        float ow = oW[idx];
        int   orr = oR[idx];
        float ex = expf((ov - THRC) * 0.5f);
        ex = fminf(ex, EXPCLIP);
        float nv = ov - DT_GL_C * (ov - ELC) + (DT_GL_C * DELTATC) * ex + (it - ow) * DT_C;
        nv = (oz > 0.5f) ? V_RESETC : nv;
        float nw = ow - DT_TAUW * ow + DTA_TAUW * (ov - ELC) + BCONST * oz;
        float nz = (nv > THRC) ? 1.0f : 0.0f;
        if (orr > 0) nz = 0.0f;
        int nr = orr - 1 + (nz > 0.5f ? 5 : 0);
        nr = nr < 0 ? 0 : (nr > 5 ? 5 : nr);
        out[idx]           = nv;
        out[CH + idx]      = nz;
        out[2 * CH + idx]  = (float)nr;
        out[3 * CH + idx]  = nw;
      }
    }
  }
}

extern "C" void kernel_launch(void* const* d_in, const int* in_sizes, int n_in,
                              void* d_out, int out_size, void* d_ws, size_t ws_size,
                              hipStream_t stream) {
  const float* X  = (const float*)d_in[0];
  const float* oV = (const float*)d_in[1];
  const int*   oR = (const int*)d_in[2];
  const float* oW = (const float*)d_in[3];
  const float* oZ = (const float*)d_in[4];
  const float* Wi = (const float*)d_in[5];
  const float* Wr = (const float*)d_in[6];
  unsigned short* AX  = (unsigned short*)d_ws;                  // 12.58 MB
  unsigned short* BT2 = AX + (size_t)M_TOT * KX;                //  3.67 MB
  char*           Zb  = (char*)(BT2 + (size_t)UNITS * 1792);    //  1.00 MB
  float* out = (float*)d_out;

  hipLaunchKernelGGL(build_ax, dim3((M_TOT * (KX / 8)) / 256), dim3(256), 0, stream, X, AX);
  hipLaunchKernelGGL(build_b,  dim3(1792 / 32, UNITS / 32), dim3(256), 0, stream, Wi, Wr, BT2);
  hipLaunchKernelGGL(build_zb, dim3((M_TOT * UNITS) / 256), dim3(256), 0, stream, oZ, Zb);
  hipLaunchKernelGGL(adex_gemm, dim3((M_TOT / BM) * (UNITS / BN)), dim3(512), 0, stream,
                     AX, BT2, Zb, oV, oR, oW, out);
}